// Round 1
// baseline (203.184 us; speedup 1.0000x reference)
//
#include <hip/hip_runtime.h>

// MultiHeadAttention: S=2048, B=2, EMB=512, H=8, D=64 -> 16 independent (b,h)
// groups of [2048 x 64] attention, plus per-head 64x64 QKV projections and a
// 512x512 output FC. All matmuls in bf16 MFMA (16x16x32), fp32 accumulate.
//
// ws layout (u16/bf16): Qb[32768*64] | Kb[32768*64] | Vt[16][64][2048] | Att[32768*64]
// total 16 MiB.

typedef __attribute__((ext_vector_type(8))) __bf16 bf16x8;
typedef __attribute__((ext_vector_type(4))) float f32x4;
typedef __attribute__((ext_vector_type(4))) unsigned short u16x4;
typedef __attribute__((ext_vector_type(4))) unsigned int u32x4;
typedef unsigned short u16;

static __device__ __forceinline__ u16 f2bf(float x) {
    unsigned int u = __float_as_uint(x);
    u += 0x7fff + ((u >> 16) & 1);   // RNE; inputs are normal floats (no NaN)
    return (u16)(u >> 16);
}

// ---------------------------------------------------------------------------
// Kernel 1: QKV projection.  Y = X @ W^T for X in {q,k,v} flat [32768 x 64],
// W [64 x 64] row-major.  mode 0/1 -> Qb/Kb row-major [32768 x 64] bf16;
// mode 2 -> Vt transposed-within-group: Vt[(g*64 + i)*2048 + s].
// Block: 256 thr / 4 waves, BM=128 (wave owns 32 rows), K=64 (no k-loop).
// LDS rows padded to 88 u16 (176 B): 16B-aligned ds_read_b128, 2-way banks.
// ---------------------------------------------------------------------------
__global__ __launch_bounds__(256) void proj_kernel(
    const float* __restrict__ q, const float* __restrict__ k, const float* __restrict__ v,
    const float* __restrict__ Wq, const float* __restrict__ Wk, const float* __restrict__ Wv,
    u16* __restrict__ Qb, u16* __restrict__ Kb, u16* __restrict__ Vt)
{
    const int mode = blockIdx.z;
    const float* A = (mode == 0) ? q : (mode == 1) ? k : v;
    const float* W = (mode == 0) ? Wq : (mode == 1) ? Wk : Wv;

    __shared__ alignas(16) u16 Ash[128 * 88];
    __shared__ alignas(16) u16 Wsh[64 * 88];

    const int t = threadIdx.x;
    const int m0 = blockIdx.x * 128;

    {   // stage A tile: 128 rows x 64 cols fp32 -> bf16 LDS
        const float4* A4 = (const float4*)(A + (size_t)m0 * 64);
        const int c4 = t & 15;
        for (int i = 0; i < 8; ++i) {
            int row = (t >> 4) + i * 16;
            float4 val = A4[row * 16 + c4];
            u16x4 bb = { f2bf(val.x), f2bf(val.y), f2bf(val.z), f2bf(val.w) };
            *(u16x4*)(Ash + row * 88 + c4 * 4) = bb;
        }
        const float4* W4 = (const float4*)W;
        for (int i = 0; i < 4; ++i) {
            int row = (t >> 4) + i * 16;
            float4 val = W4[row * 16 + c4];
            u16x4 bb = { f2bf(val.x), f2bf(val.y), f2bf(val.z), f2bf(val.w) };
            *(u16x4*)(Wsh + row * 88 + c4 * 4) = bb;
        }
    }
    __syncthreads();

    const int w = t >> 6, l = t & 63;
    const int r16 = l & 15, q4 = l >> 4;

    bf16x8 af[2][2], wf[4][2];
    for (int mc = 0; mc < 2; ++mc)
        for (int kk = 0; kk < 2; ++kk)
            af[mc][kk] = *(const bf16x8*)(Ash + (w * 32 + mc * 16 + r16) * 88 + kk * 32 + q4 * 8);
    for (int nc = 0; nc < 4; ++nc)
        for (int kk = 0; kk < 2; ++kk)
            wf[nc][kk] = *(const bf16x8*)(Wsh + (nc * 16 + r16) * 88 + kk * 32 + q4 * 8);

    f32x4 acc[2][4];
    const f32x4 zero = {0.f, 0.f, 0.f, 0.f};
    for (int mc = 0; mc < 2; ++mc)
        for (int nc = 0; nc < 4; ++nc) {
            acc[mc][nc] = zero;
            acc[mc][nc] = __builtin_amdgcn_mfma_f32_16x16x32_bf16(af[mc][0], wf[nc][0], acc[mc][nc], 0, 0, 0);
            acc[mc][nc] = __builtin_amdgcn_mfma_f32_16x16x32_bf16(af[mc][1], wf[nc][1], acc[mc][nc], 0, 0, 0);
        }

    // C/D layout: col = lane&15, row = quad*4 + reg
    if (mode < 2) {
        u16* Out = (mode == 0) ? Qb : Kb;
        for (int mc = 0; mc < 2; ++mc)
            for (int nc = 0; nc < 4; ++nc)
                for (int r = 0; r < 4; ++r) {
                    int row = m0 + w * 32 + mc * 16 + q4 * 4 + r;
                    int col = nc * 16 + r16;
                    Out[(size_t)row * 64 + col] = f2bf(acc[mc][nc][r]);
                }
    } else {
        for (int mc = 0; mc < 2; ++mc)
            for (int nc = 0; nc < 4; ++nc)
                for (int r = 0; r < 4; ++r) {
                    int sg = m0 + w * 32 + mc * 16 + q4 * 4 + r;
                    int g = sg >> 11, s = sg & 2047;
                    int col = nc * 16 + r16;
                    Vt[((size_t)(g * 64 + col)) * 2048 + s] = f2bf(acc[mc][nc][r]);
                }
    }
}

// ---------------------------------------------------------------------------
// Kernel 2: flash attention per (group, 64-row Q tile).  4 waves x 16 q rows.
// K-tile = 32 keys/iter, D = 64.  QK^T and PV via mfma_f32_16x16x32_bf16.
// Online softmax in exp2 domain.  P goes C-layout -> LDS -> A-layout (m120).
// ---------------------------------------------------------------------------
__global__ __launch_bounds__(256) void flash_kernel(
    const u16* __restrict__ Qb, const u16* __restrict__ Kb,
    const u16* __restrict__ Vt, u16* __restrict__ Att)
{
    const int g = blockIdx.y;    // 0..15
    const int qt = blockIdx.x;   // 0..31
    const int t = threadIdx.x, w = t >> 6, l = t & 63;
    const int r16 = l & 15, q4 = l >> 4;

    __shared__ alignas(16) u16 Ksh[32 * 88];      // [key][d], pad 64->88
    __shared__ alignas(16) u16 Vsh[64 * 40];      // [d][key], pad 32->40
    __shared__ alignas(16) u16 Psh[4][16 * 40];   // per-wave [q][key], pad 32->40

    // Q fragments (A-operand): lane holds Q[row = base + (l&15)][k = q4*8+j]
    const int qrow = qt * 64 + w * 16 + r16;
    bf16x8 qa[2];
    {
        const u16* qp = Qb + ((size_t)(g * 2048 + qrow)) * 64 + q4 * 8;
        qa[0] = *(const bf16x8*)qp;
        qa[1] = *(const bf16x8*)(qp + 32);
    }

    f32x4 o[4];
    const f32x4 zero = {0.f, 0.f, 0.f, 0.f};
    for (int c = 0; c < 4; ++c) o[c] = zero;
    float m2[4], lsum[4];
    for (int r = 0; r < 4; ++r) { m2[r] = -INFINITY; lsum[r] = 0.f; }
    const float sc2 = 0.125f * 1.44269504088896340736f;  // (1/sqrt(64)) * log2(e)

    for (int kt = 0; kt < 64; ++kt) {
        __syncthreads();  // previous iter's LDS reads done before overwrite
        {   // stage K tile: 32 keys x 64 d  (u32x4 = 8 bf16 per thread)
            int key = t >> 3, c8 = t & 7;
            *(u32x4*)(Ksh + key * 88 + c8 * 8) =
                *(const u32x4*)(Kb + ((size_t)(g * 2048 + kt * 32 + key)) * 64 + c8 * 8);
            // stage Vt tile: 64 d x 32 keys
            int d = t >> 2, c8v = t & 3;
            *(u32x4*)(Vsh + d * 40 + c8v * 8) =
                *(const u32x4*)(Vt + ((size_t)(g * 64 + d)) * 2048 + kt * 32 + c8v * 8);
        }
        __syncthreads();

        // S = Q @ K^T : two 16-key chunks; B-frag = K row (kc*16+(l&15)), d = q4*8..
        f32x4 s[2];
        for (int kc = 0; kc < 2; ++kc) {
            const u16* kp = Ksh + (kc * 16 + r16) * 88 + q4 * 8;
            bf16x8 b0 = *(const bf16x8*)kp;
            bf16x8 b1 = *(const bf16x8*)(kp + 32);
            s[kc] = zero;
            s[kc] = __builtin_amdgcn_mfma_f32_16x16x32_bf16(qa[0], b0, s[kc], 0, 0, 0);
            s[kc] = __builtin_amdgcn_mfma_f32_16x16x32_bf16(qa[1], b1, s[kc], 0, 0, 0);
        }

        // online softmax (rows live across the 16 lanes sharing q4)
        float p0[4], p1[4], alpha[4];
        for (int r = 0; r < 4; ++r) {
            float x0 = s[0][r] * sc2, x1 = s[1][r] * sc2;
            float mx = fmaxf(x0, x1);
            mx = fmaxf(mx, __shfl_xor(mx, 1));
            mx = fmaxf(mx, __shfl_xor(mx, 2));
            mx = fmaxf(mx, __shfl_xor(mx, 4));
            mx = fmaxf(mx, __shfl_xor(mx, 8));
            float mn = fmaxf(m2[r], mx);
            float a = exp2f(m2[r] - mn);
            p0[r] = exp2f(x0 - mn);
            p1[r] = exp2f(x1 - mn);
            float ps = p0[r] + p1[r];
            ps += __shfl_xor(ps, 1);
            ps += __shfl_xor(ps, 2);
            ps += __shfl_xor(ps, 4);
            ps += __shfl_xor(ps, 8);
            lsum[r] = lsum[r] * a + ps;
            m2[r] = mn;
            alpha[r] = a;
        }
        for (int c = 0; c < 4; ++c)
            for (int r = 0; r < 4; ++r) o[c][r] *= alpha[r];

        // P: C-layout (row=q4*4+r, col=kc*16+r16) -> LDS -> A-layout
        u16* pw = Psh[w];
        for (int r = 0; r < 4; ++r) {
            pw[(q4 * 4 + r) * 40 + r16]      = f2bf(p0[r]);
            pw[(q4 * 4 + r) * 40 + 16 + r16] = f2bf(p1[r]);
        }
        __syncthreads();  // also covers per-wave P write->read visibility

        bf16x8 pa = *(const bf16x8*)(pw + r16 * 40 + q4 * 8);   // A[m=l&15][k=q4*8+j]
        for (int c = 0; c < 4; ++c) {
            bf16x8 bv = *(const bf16x8*)(Vsh + (c * 16 + r16) * 40 + q4 * 8);
            o[c] = __builtin_amdgcn_mfma_f32_16x16x32_bf16(pa, bv, o[c], 0, 0, 0);
        }
    }

    // epilogue: normalize and store att tile (bf16)
    float inv[4];
    for (int r = 0; r < 4; ++r) inv[r] = 1.0f / lsum[r];
    for (int c = 0; c < 4; ++c)
        for (int r = 0; r < 4; ++r) {
            int qq = qt * 64 + w * 16 + q4 * 4 + r;
            Att[((size_t)(g * 2048 + qq)) * 64 + c * 16 + r16] = f2bf(o[c][r] * inv[r]);
        }
}

// ---------------------------------------------------------------------------
// Kernel 3: out = Att @ Wfc^T + bfc.  M=4096, N=512, K=512.
// BM=128, BN=64, BK=64; grid (32, 8) = 256 blocks.  fp32 output.
// ---------------------------------------------------------------------------
__global__ __launch_bounds__(256) void fc_kernel(
    const u16* __restrict__ Att, const float* __restrict__ Wfc,
    const float* __restrict__ bfc, float* __restrict__ out)
{
    __shared__ alignas(16) u16 Ash[128 * 88];
    __shared__ alignas(16) u16 Wsh[64 * 88];

    const int t = threadIdx.x, w = t >> 6, l = t & 63;
    const int r16 = l & 15, q4 = l >> 4;
    const int m0 = blockIdx.x * 128, n0 = blockIdx.y * 64;

    f32x4 acc[2][4];
    const f32x4 zero = {0.f, 0.f, 0.f, 0.f};
    for (int mc = 0; mc < 2; ++mc)
        for (int nc = 0; nc < 4; ++nc) acc[mc][nc] = zero;

    for (int k0 = 0; k0 < 512; k0 += 64) {
        __syncthreads();
        {   // stage A (bf16 already): 128 x 64
            int c8 = t & 7;
            for (int i = 0; i < 4; ++i) {
                int row = (t >> 3) + i * 32;
                *(u32x4*)(Ash + row * 88 + c8 * 8) =
                    *(const u32x4*)(Att + (size_t)(m0 + row) * 512 + k0 + c8 * 8);
            }
            // stage W (fp32 -> bf16): rows n0..n0+63, cols k0..k0+63
            int row = t >> 2;
            for (int i = 0; i < 4; ++i) {
                int c4 = (t & 3) + i * 4;
                float4 val = *(const float4*)(Wfc + (size_t)(n0 + row) * 512 + k0 + c4 * 4);
                u16x4 bb = { f2bf(val.x), f2bf(val.y), f2bf(val.z), f2bf(val.w) };
                *(u16x4*)(Wsh + row * 88 + c4 * 4) = bb;
            }
        }
        __syncthreads();

        bf16x8 af[2][2], wf[4][2];
        for (int mc = 0; mc < 2; ++mc)
            for (int kk = 0; kk < 2; ++kk)
                af[mc][kk] = *(const bf16x8*)(Ash + (w * 32 + mc * 16 + r16) * 88 + kk * 32 + q4 * 8);
        for (int nc = 0; nc < 4; ++nc)
            for (int kk = 0; kk < 2; ++kk)
                wf[nc][kk] = *(const bf16x8*)(Wsh + (nc * 16 + r16) * 88 + kk * 32 + q4 * 8);

        for (int mc = 0; mc < 2; ++mc)
            for (int nc = 0; nc < 4; ++nc) {
                acc[mc][nc] = __builtin_amdgcn_mfma_f32_16x16x32_bf16(af[mc][0], wf[nc][0], acc[mc][nc], 0, 0, 0);
                acc[mc][nc] = __builtin_amdgcn_mfma_f32_16x16x32_bf16(af[mc][1], wf[nc][1], acc[mc][nc], 0, 0, 0);
            }
    }

    for (int mc = 0; mc < 2; ++mc)
        for (int nc = 0; nc < 4; ++nc)
            for (int r = 0; r < 4; ++r) {
                int row = m0 + w * 32 + mc * 16 + q4 * 4 + r;
                int col = n0 + nc * 16 + r16;
                out[(size_t)row * 512 + col] = acc[mc][nc][r] + bfc[col];
            }
}

extern "C" void kernel_launch(void* const* d_in, const int* in_sizes, int n_in,
                              void* d_out, int out_size, void* d_ws, size_t ws_size,
                              hipStream_t stream) {
    (void)in_sizes; (void)n_in; (void)out_size; (void)ws_size;
    const float* q   = (const float*)d_in[0];
    const float* k   = (const float*)d_in[1];
    const float* v   = (const float*)d_in[2];
    const float* Wq  = (const float*)d_in[3];
    const float* Wk  = (const float*)d_in[4];
    const float* Wv  = (const float*)d_in[5];
    const float* Wfc = (const float*)d_in[6];
    const float* bfc = (const float*)d_in[7];
    float* out = (float*)d_out;

    u16* Qb = (u16*)d_ws;                 // 32768*64 bf16
    u16* Kb = Qb + 2097152;
    u16* Vt = Kb + 2097152;               // [16][64][2048]
    u16* At = Vt + 2097152;               // 32768*64 bf16
    // total ws use: 16 MiB

    proj_kernel<<<dim3(256, 1, 3), 256, 0, stream>>>(q, k, v, Wq, Wk, Wv, Qb, Kb, Vt);
    flash_kernel<<<dim3(32, 16), 256, 0, stream>>>(Qb, Kb, Vt, At);
    fc_kernel<<<dim3(32, 8), 256, 0, stream>>>(At, Wfc, bfc, out);
}